// Round 3
// baseline (260.823 us; speedup 1.0000x reference)
//
#include <hip/hip_runtime.h>
#include <hip/hip_bf16.h>
#include <hip/hip_cooperative_groups.h>
#include <stdint.h>

namespace cg = cooperative_groups;

#define SEQ   2048
#define DIM   512
#define BATCH 4

typedef __attribute__((ext_vector_type(8))) short  short8;
typedef __attribute__((ext_vector_type(4))) float  floatx4;

static __device__ __forceinline__ unsigned short f2b(float f) {
  return __builtin_bit_cast(unsigned short, __float2bfloat16(f));
}

// async 16B/lane global->LDS (global_load_lds_dwordx4)
static __device__ __forceinline__ void gll16(const void* g, void* l) {
  __builtin_amdgcn_global_load_lds(
      (__attribute__((address_space(1))) void*)(uintptr_t)g,
      (__attribute__((address_space(3))) void*)l, 16, 0, 0);
}

// ---------------------------------------------------------------------------
// Fragment-linear layout (verified): logical [R rows][K] bf16 matrix as 1KB
// fragments of 16 rows x 32 k; frag index = rt*TK + kt; within a frag, lane l
// owns bytes l*16..+15 = MFMA operand row rt*16+(l&15), k octet (l>>4).
// ---------------------------------------------------------------------------

// Phase-interleaved fragment GEMM: 4-slot LDS ring, 3-deep prefetch, counted
// vmcnt ladder (2L -> L -> 0), per-phase {ds_read || stage -> barrier ->
// lgkmcnt(0) -> setprio(1) MFMA setprio(0) -> barrier}.  No other VMEM ops may
// be outstanding when the counted waits execute (callers guarantee).
template <int AF, int BF, int WM, int WN, int KC, int PH, int KIT>
__device__ __forceinline__ void fgemm_8p(
    const char* __restrict__ A, int rtA0, int TKA,
    const char* __restrict__ B, int rtB0, int TKB,
    char* lds, floatx4 (&acc)[AF / WM][BF / WN])
{
  constexpr int AWF  = AF / WM, BWF = BF / WN;
  constexpr int SLOT = (AF + BF) * KC * 1024;
  constexpr int L    = KC * (AF / 8 + BF / 8);   // gll16 per wave per slot
  constexpr int AC   = AWF / PH;                 // A-frag rows per phase
  static_assert(KIT >= 3, "pipeline needs >=3 K-slots");
  static_assert(AWF % PH == 0 && L % PH == 0, "phase split must divide");
  const int tid = threadIdx.x;
  const int w = tid >> 6, l = tid & 63;
  const int wm = w % WM, wn = w / WM;

  auto stage_part = [&](int slot, int kt, int p) {
    char* dst = lds + slot * SLOT;
#pragma unroll
    for (int g = p * (L / PH); g < (p + 1) * (L / PH); ++g) {
      if (g < KC * (AF / 8)) {
        const int c = g / (AF / 8), q = g % (AF / 8);
        const int f = q * 8 + w;
        gll16(A + (((size_t)(rtA0 + f) * TKA + kt * KC + c) << 10) + l * 16,
              dst + (c * AF + f) * 1024 + l * 16);
      } else {
        const int h = g - KC * (AF / 8);
        const int c = h / (BF / 8), q = h % (BF / 8);
        const int f = q * 8 + w;
        gll16(B + (((size_t)(rtB0 + f) * TKB + kt * KC + c) << 10) + l * 16,
              dst + (KC * AF + c * BF + f) * 1024 + l * 16);
      }
    }
  };
  auto stage_all = [&](int slot, int kt) {
#pragma unroll
    for (int p = 0; p < PH; ++p) stage_part(slot, kt, p);
  };

  // Prologue: 3 slots in flight; publish slot 0 (wait only its L loads).
  stage_all(0, 0); stage_all(1, 1); stage_all(2, 2);
  asm volatile("s_waitcnt vmcnt(%0) lgkmcnt(0)\ns_barrier" :: "n"(2 * L) : "memory");

  short8 bf[KC][BWF];
#pragma unroll 4
  for (int kt = 0; kt < KIT; ++kt) {
    const char* bA = lds + (kt & 3) * SLOT;
    const char* bB = bA + KC * AF * 1024;
#pragma unroll
    for (int p = 0; p < PH; ++p) {
      short8 af[KC][AC];
#pragma unroll
      for (int c = 0; c < KC; ++c)
#pragma unroll
        for (int i = 0; i < AC; ++i)
          af[c][i] = *(const short8*)(bA + (c * AF + wm * AWF + p * AC + i) * 1024 + l * 16);
      if (p == 0) {
#pragma unroll
        for (int c = 0; c < KC; ++c)
#pragma unroll
          for (int j = 0; j < BWF; ++j)
            bf[c][j] = *(const short8*)(bB + (c * BF + wn * BWF + j) * 1024 + l * 16);
      }
      if (kt + 3 < KIT) stage_part((kt + 3) & 3, kt + 3, p);   // 3-ahead prefetch

      asm volatile("s_barrier" ::: "memory");
      asm volatile("s_waitcnt lgkmcnt(0)" ::: "memory");
      __builtin_amdgcn_s_setprio(1);
#pragma unroll
      for (int c = 0; c < KC; ++c)
#pragma unroll
        for (int i = 0; i < AC; ++i)
#pragma unroll
          for (int j = 0; j < BWF; ++j)
            acc[p * AC + i][j] = __builtin_amdgcn_mfma_f32_16x16x32_bf16(
                af[c][i], bf[c][j], acc[p * AC + i][j], 0, 0, 0);
      __builtin_amdgcn_s_setprio(0);

      if (p == PH - 1) {        // slot-closing barrier: counted vmcnt ladder
        if (kt + 3 < KIT)
          asm volatile("s_waitcnt vmcnt(%0)\ns_barrier" :: "n"(2 * L) : "memory");
        else if (kt + 2 < KIT)
          asm volatile("s_waitcnt vmcnt(%0)\ns_barrier" :: "n"(L) : "memory");
        else if (kt + 1 < KIT)
          asm volatile("s_waitcnt vmcnt(0)\ns_barrier" ::: "memory");
        // last slot: fall through to epilogue (all gll16 retired by ladder)
      } else {
        asm volatile("s_barrier" ::: "memory");
      }
    }
  }
}

// ======================= phase bodies (shared) =============================

// Setup (mega version: 256 blocks x 512 threads; each thread 4 X-units).
static __device__ __forceinline__ void do_setup(
    int blk, const float* __restrict__ X, const float* __restrict__ Wq,
    const float* __restrict__ Wk, const float* __restrict__ Wv,
    short8* __restrict__ XbF, short8* __restrict__ WF)
{
#pragma unroll
  for (int u = 0; u < 4; ++u) {
    const int flat = blk * 2048 + u * 512 + (int)threadIdx.x;  // 0..524287
    const int tile = flat >> 6, l = flat & 63;
    const int row = (tile >> 4) * 16 + (l & 15);
    const int k0  = (tile & 15) * 32 + (l >> 4) * 8;
    const float4 v0 = *(const float4*)(X + (size_t)row * DIM + k0);
    const float4 v1 = *(const float4*)(X + (size_t)row * DIM + k0 + 4);
    short8 o;
    o[0] = (short)f2b(v0.x); o[1] = (short)f2b(v0.y);
    o[2] = (short)f2b(v0.z); o[3] = (short)f2b(v0.w);
    o[4] = (short)f2b(v1.x); o[5] = (short)f2b(v1.y);
    o[6] = (short)f2b(v1.z); o[7] = (short)f2b(v1.w);
    XbF[flat] = o;
  }
  const int fl = blk * 512 + (int)threadIdx.x;
  if (fl < 3 * 32768) {                            // W -> WF (rows=n, K=k)
    const int z = fl >> 15, within = fl & 32767;
    const float* W = (z == 0) ? Wq : (z == 1) ? Wk : Wv;
    const int tile = within >> 6, l = within & 63;
    const int n  = (tile >> 4) * 16 + (l & 15);
    const int k0 = (tile & 15) * 32 + (l >> 4) * 8;
    short8 o;
#pragma unroll
    for (int e = 0; e < 8; ++e)
      o[e] = (short)f2b(W[(size_t)(k0 + e) * DIM + n]);
    WF[fl] = o;
  }
}

// QKV job: z=0,1: C[d][s] 256x256 (A=WF, B=XbF) -> QF/KF; z=2: C[s][d]
// 256x256 (A=XbF, B=WFv) -> VF.
static __device__ __forceinline__ void do_qkv(
    int z, int job, char* lds, const short8* __restrict__ XbF,
    const short8* __restrict__ WF, const float* __restrict__ bq,
    const float* __restrict__ bk, const float* __restrict__ bv,
    unsigned short* __restrict__ QF, unsigned short* __restrict__ KF,
    unsigned short* __restrict__ VF)
{
  const int lane = threadIdx.x & 63, w = threadIdx.x >> 6;
  const int wm = w & 1, wn = w >> 1;             // WM=2, WN=4
  const int x = job & 31, y = job >> 5;
  const char* Xc = (const char*)XbF;
  const char* Wc = (const char*)WF;
  floatx4 acc[8][4] = {};

  if (z < 2) {
    fgemm_8p<16, 16, 2, 4, 1, 2, 16>(Wc + (size_t)z * 524288, y * 16, 16,
                                     Xc, x * 16, 16, lds, acc);
    const float* bias = z ? bk : bq;
    unsigned short* OF = z ? KF : QF;
    const int dbase = y * 256 + wm * 128;
    const int sbase = x * 256 + wn * 64;
#pragma unroll
    for (int i = 0; i < 8; ++i) {
      const int d0 = dbase + i * 16 + (lane >> 4) * 4;
      const float4 b4 = *(const float4*)(bias + d0);
#pragma unroll
      for (int j = 0; j < 4; ++j) {
        const int s = sbase + j * 16 + (lane & 15);
        ushort4 pk;
        pk.x = f2b(acc[i][j][0] + b4.x);
        pk.y = f2b(acc[i][j][1] + b4.y);
        pk.z = f2b(acc[i][j][2] + b4.z);
        pk.w = f2b(acc[i][j][3] + b4.w);
        *(ushort4*)(OF + (size_t)((s >> 4) * 16 + (d0 >> 5)) * 512 +
                    ((((d0 & 31) >> 3) << 4) | (s & 15)) * 8 + (d0 & 7)) = pk;
      }
    }
  } else {
    fgemm_8p<16, 16, 2, 4, 1, 2, 16>(Xc, x * 16, 16,
                                     Wc + 2 * 524288, y * 16, 16, lds, acc);
    const int sbase = x * 256 + wm * 128;
    const int dbase = y * 256 + wn * 64;
#pragma unroll
    for (int i = 0; i < 8; ++i) {
      const int s0 = sbase + i * 16 + (lane >> 4) * 4;
      const int bt = s0 >> 11, t0 = s0 & 2047;
#pragma unroll
      for (int j = 0; j < 4; ++j) {
        const int d = dbase + j * 16 + (lane & 15);
        const float bn = bv[d];
        ushort4 pk;
        pk.x = f2b(acc[i][j][0] + bn);
        pk.y = f2b(acc[i][j][1] + bn);
        pk.z = f2b(acc[i][j][2] + bn);
        pk.w = f2b(acc[i][j][3] + bn);
        *(ushort4*)(VF + (size_t)bt * DIM * SEQ +
                    (size_t)((d >> 4) * 64 + (t0 >> 5)) * 512 +
                    ((((t0 & 31) >> 3) << 4) | (d & 15)) * 8 + (t0 & 7)) = pk;
      }
    }
  }
}

// Scores job: S^T = K Q^T (256t x 256s) -> exp -> ScF frags + partial rowsum
// slice prow[y*2+wm][b][s] (plain stores, no atomics; every slot written
// exactly once: (q,b,s) <-> unique (block, wave)).
static __device__ __forceinline__ void do_scores(
    int b, int x, int y, char* lds, const unsigned short* __restrict__ QF,
    const unsigned short* __restrict__ KF, unsigned short* __restrict__ ScF,
    float* __restrict__ prow)
{
  const int lane = threadIdx.x & 63, w = threadIdx.x >> 6;
  const int wm = w & 1, wn = w >> 1;             // WM=2, WN=4
  floatx4 acc[8][4] = {};
  fgemm_8p<16, 16, 2, 4, 1, 2, 16>((const char*)KF + (size_t)b * 2097152, y * 16, 16,
                                   (const char*)QF + (size_t)b * 2097152, x * 16, 16,
                                   lds, acc);

  unsigned short* S = ScF + (size_t)b * SEQ * SEQ;
  const float scale = 0.044194173824159216f;  // 1/sqrt(512)
  const int tbase = y * 256 + wm * 128;
  const int sbase = x * 256 + wn * 64;
  float colsum[4] = {0.f, 0.f, 0.f, 0.f};
#pragma unroll
  for (int i = 0; i < 8; ++i) {
    const int t0 = tbase + i * 16 + (lane >> 4) * 4;
#pragma unroll
    for (int j = 0; j < 4; ++j) {
      const int s = sbase + j * 16 + (lane & 15);
      float e0 = __expf(acc[i][j][0] * scale);
      float e1 = __expf(acc[i][j][1] * scale);
      float e2 = __expf(acc[i][j][2] * scale);
      float e3 = __expf(acc[i][j][3] * scale);
      colsum[j] += (e0 + e1) + (e2 + e3);
      ushort4 pk;
      pk.x = f2b(e0); pk.y = f2b(e1); pk.z = f2b(e2); pk.w = f2b(e3);
      *(ushort4*)(S + (size_t)((s >> 4) * 64 + (t0 >> 5)) * 512 +
                  ((((t0 & 31) >> 3) << 4) | (s & 15)) * 8 + (t0 & 7)) = pk;
    }
  }
#pragma unroll
  for (int j = 0; j < 4; ++j) {
    colsum[j] += __shfl_xor(colsum[j], 16, 64);
    colsum[j] += __shfl_xor(colsum[j], 32, 64);
  }
  if (lane < 16) {
    float* dst = prow + ((size_t)(y * 2 + wm) * BATCH + b) * SEQ + sbase + lane;
#pragma unroll
    for (int j = 0; j < 4; ++j) dst[j * 16] = colsum[j];
  }
}

// PV job: out[s][d] = (ScF . VF) * rinv[s]; 128x128 tile, BK=64. rinv built
// from the 16 partial slices in a pre-pass (before the pipelined GEMM, so its
// VMEM loads are compiler-drained before the counted-vmcnt loop).
static __device__ __forceinline__ void do_pv(
    int b, int x, int y, char* lds, float* rinv,
    const unsigned short* __restrict__ ScF, const unsigned short* __restrict__ VF,
    const float* __restrict__ prow, float* __restrict__ out)
{
  const int t = threadIdx.x;
  if (t < 128) {
    const int s = x * 128 + t;
    float r = 0.f;
#pragma unroll
    for (int q = 0; q < 16; ++q) r += prow[((size_t)q * BATCH + b) * SEQ + s];
    rinv[t] = 1.f / r;
  }
  const int lane = threadIdx.x & 63, w = threadIdx.x >> 6;
  const int wm = w & 1, wn = w >> 1;             // WM=2, WN=4
  floatx4 acc[4][2] = {};
  fgemm_8p<8, 8, 2, 4, 2, 1, 32>((const char*)ScF + (size_t)b * 8388608, x * 8, 64,
                                 (const char*)VF + (size_t)b * 2097152, y * 8, 64,
                                 lds, acc);

  const int mbase = x * 128 + wm * 64;
  const int dbase = y * 128 + wn * 32;
#pragma unroll
  for (int i = 0; i < 4; ++i) {
    const int r0 = wm * 64 + i * 16 + (lane >> 4) * 4;
    const int m0 = mbase + i * 16 + (lane >> 4) * 4;
    const float inv0 = rinv[r0], inv1 = rinv[r0 + 1], inv2 = rinv[r0 + 2], inv3 = rinv[r0 + 3];
#pragma unroll
    for (int j = 0; j < 2; ++j) {
      const int d = dbase + j * 16 + (lane & 15);
      float* o = out + ((size_t)b * SEQ + m0) * DIM + d;
      o[0 * DIM] = acc[i][j][0] * inv0;
      o[1 * DIM] = acc[i][j][1] * inv1;
      o[2 * DIM] = acc[i][j][2] * inv2;
      o[3 * DIM] = acc[i][j][3] * inv3;
    }
  }
}

// ======================= mega cooperative kernel ===========================
__global__ __launch_bounds__(512, 2) void mega_kernel(
    const float* X, const float* Wq, const float* Wk, const float* Wv,
    const float* bq, const float* bk, const float* bv,
    short8* XbF, short8* WF, unsigned short* QF, unsigned short* KF,
    unsigned short* VF, unsigned short* ScF, float* prow, float* out)
{
  __shared__ char lds[131072];   // 4 x 32 KB ring
  __shared__ float rinv[128];
  cg::grid_group grid = cg::this_grid();
  const int blk = blockIdx.x;    // 0..255, 1 block/CU (LDS-bound)

  do_setup(blk, X, Wq, Wk, Wv, XbF, WF);
  grid.sync();
  if (blk < 192) do_qkv(blk >> 6, blk & 63, lds, XbF, WF, bq, bk, bv, QF, KF, VF);
  grid.sync();
  { const int b = blk >> 6, r = blk & 63;
    do_scores(b, r & 7, r >> 3, lds, QF, KF, ScF, prow); }
  grid.sync();
  { const int b = blk >> 6, r = blk & 63;
    do_pv(b, r >> 2, r & 3, lds, rinv, ScF, VF, prow, out); }
}

// ======================= fallback standalone kernels =======================
__global__ __launch_bounds__(256) void setup_kernel(
    const float* __restrict__ X, const float* __restrict__ Wq,
    const float* __restrict__ Wk, const float* __restrict__ Wv,
    short8* __restrict__ XbF, short8* __restrict__ WF)
{
  const int flat = blockIdx.x * 256 + threadIdx.x;   // 0..524287
  {
    const int tile = flat >> 6, l = flat & 63;
    const int row = (tile >> 4) * 16 + (l & 15);
    const int k0  = (tile & 15) * 32 + (l >> 4) * 8;
    const float4 v0 = *(const float4*)(X + (size_t)row * DIM + k0);
    const float4 v1 = *(const float4*)(X + (size_t)row * DIM + k0 + 4);
    short8 o;
    o[0] = (short)f2b(v0.x); o[1] = (short)f2b(v0.y);
    o[2] = (short)f2b(v0.z); o[3] = (short)f2b(v0.w);
    o[4] = (short)f2b(v1.x); o[5] = (short)f2b(v1.y);
    o[6] = (short)f2b(v1.z); o[7] = (short)f2b(v1.w);
    XbF[flat] = o;
  }
  if (flat < 3 * 32768) {
    const int z = flat >> 15, within = flat & 32767;
    const float* W = (z == 0) ? Wq : (z == 1) ? Wk : Wv;
    const int tile = within >> 6, l = within & 63;
    const int n  = (tile >> 4) * 16 + (l & 15);
    const int k0 = (tile & 15) * 32 + (l >> 4) * 8;
    short8 o;
#pragma unroll
    for (int e = 0; e < 8; ++e)
      o[e] = (short)f2b(W[(size_t)(k0 + e) * DIM + n]);
    WF[flat] = o;
  }
}

__global__ __launch_bounds__(512, 2) void qkv_kernel(
    const short8* __restrict__ XbF, const short8* __restrict__ WF,
    const float* __restrict__ bq, const float* __restrict__ bk,
    const float* __restrict__ bv,
    unsigned short* __restrict__ QF, unsigned short* __restrict__ KF,
    unsigned short* __restrict__ VF)
{
  __shared__ char lds[131072];
  do_qkv(blockIdx.z, blockIdx.x, lds, XbF, WF, bq, bk, bv, QF, KF, VF);
}

__global__ __launch_bounds__(512, 2) void scores_kernel(
    const unsigned short* __restrict__ QF, const unsigned short* __restrict__ KF,
    unsigned short* __restrict__ ScF, float* __restrict__ prow)
{
  __shared__ char lds[131072];
  do_scores(blockIdx.z, blockIdx.x, blockIdx.y, lds, QF, KF, ScF, prow);
}

__global__ __launch_bounds__(512, 2) void pv_kernel(
    const unsigned short* __restrict__ ScF, const unsigned short* __restrict__ VF,
    const float* __restrict__ prow, float* __restrict__ out)
{
  __shared__ char lds[131072];
  __shared__ float rinv[128];
  do_pv(blockIdx.z, blockIdx.x, blockIdx.y, lds, rinv, ScF, VF, prow, out);
}

extern "C" void kernel_launch(void* const* d_in, const int* in_sizes, int n_in,
                              void* d_out, int out_size, void* d_ws, size_t ws_size,
                              hipStream_t stream) {
  const float* X  = (const float*)d_in[0];
  const float* Wq = (const float*)d_in[1];
  const float* bq = (const float*)d_in[2];
  const float* Wk = (const float*)d_in[3];
  const float* bk = (const float*)d_in[4];
  const float* Wv = (const float*)d_in[5];
  const float* bv = (const float*)d_in[6];
  float* out = (float*)d_out;
  char* ws = (char*)d_ws;

  // workspace layout (bytes). prow aliases XbF (XbF is dead after qkv).
  short8* XbF = (short8*)(ws + 0);                    //  8 MB   (rows=b*S+s, K=512)
  float*  prow = (float*)(ws + 0);                    // 512 KB  [16][B][SEQ] partial rowsums
  short8* WF  = (short8*)(ws + 8388608);              //  1.5 MB (rows=n, K=512, x3)
  unsigned short* QF  = (unsigned short*)(ws + 9961472);   //  8 MB
  unsigned short* KF  = (unsigned short*)(ws + 18350080);  //  8 MB
  unsigned short* VF  = (unsigned short*)(ws + 26738688);  //  8 MB
  unsigned short* ScF = (unsigned short*)(ws + 35127296);  // 32 MB

  void* args[] = {
    (void*)&X, (void*)&Wq, (void*)&Wk, (void*)&Wv,
    (void*)&bq, (void*)&bk, (void*)&bv,
    (void*)&XbF, (void*)&WF, (void*)&QF, (void*)&KF,
    (void*)&VF, (void*)&ScF, (void*)&prow, (void*)&out
  };
  hipError_t e = hipLaunchCooperativeKernel(
      (const void*)mega_kernel, dim3(256), dim3(512), args, 0, stream);
  if (e != hipSuccess) {
    (void)hipGetLastError();   // clear sticky error, fall back to 4 launches
    setup_kernel<<<dim3(2048), 256, 0, stream>>>(X, Wq, Wk, Wv, XbF, WF);
    qkv_kernel<<<dim3(64, 1, 3), 512, 0, stream>>>(XbF, WF, bq, bk, bv, QF, KF, VF);
    scores_kernel<<<dim3(8, 8, 4), 512, 0, stream>>>(QF, KF, ScF, prow);
    pv_kernel<<<dim3(16, 4, 4), 512, 0, stream>>>(ScF, VF, prow, out);
  }
}

// Round 4
// 142.792 us; speedup vs baseline: 1.8266x; 1.8266x over previous
//
#include <hip/hip_runtime.h>
#include <hip/hip_bf16.h>
#include <stdint.h>

#define SEQ   2048
#define DIM   512
#define BATCH 4

typedef __attribute__((ext_vector_type(8))) short  short8;
typedef __attribute__((ext_vector_type(4))) float  floatx4;

static __device__ __forceinline__ unsigned short f2b(float f) {
  return __builtin_bit_cast(unsigned short, __float2bfloat16(f));
}

// async 16B/lane global->LDS (global_load_lds_dwordx4)
static __device__ __forceinline__ void gll16(const void* g, void* l) {
  __builtin_amdgcn_global_load_lds(
      (__attribute__((address_space(1))) void*)(uintptr_t)g,
      (__attribute__((address_space(3))) void*)l, 16, 0, 0);
}

// ---------------------------------------------------------------------------
// Fragment-linear layout (verified): logical [R rows][K] bf16 matrix as 1KB
// fragments of 16 rows x 32 k; frag index = rt*TK + kt; within a frag, lane l
// owns bytes l*16..+15 = MFMA operand row rt*16+(l&15), k octet (l>>4).
// ---------------------------------------------------------------------------

// Phase-interleaved fragment GEMM: 4-slot LDS ring, 3-deep prefetch, counted
// vmcnt ladder (2L -> L -> 0), per-phase {ds_read || stage -> barrier ->
// lgkmcnt(0) -> setprio(1) MFMA setprio(0) -> barrier}.  Callers guarantee no
// other VMEM op is outstanding when the counted waits execute.
template <int AF, int BF, int WM, int WN, int KC, int PH, int KIT>
__device__ __forceinline__ void fgemm_8p(
    const char* __restrict__ A, int rtA0, int TKA,
    const char* __restrict__ B, int rtB0, int TKB,
    char* lds, floatx4 (&acc)[AF / WM][BF / WN])
{
  constexpr int AWF  = AF / WM, BWF = BF / WN;
  constexpr int SLOT = (AF + BF) * KC * 1024;
  constexpr int L    = KC * (AF / 8 + BF / 8);   // gll16 per wave per slot
  constexpr int AC   = AWF / PH;                 // A-frag rows per phase
  static_assert(KIT >= 3, "pipeline needs >=3 K-slots");
  static_assert(AWF % PH == 0 && L % PH == 0, "phase split must divide");
  const int tid = threadIdx.x;
  const int w = tid >> 6, l = tid & 63;
  const int wm = w % WM, wn = w / WM;

  auto stage_part = [&](int slot, int kt, int p) {
    char* dst = lds + slot * SLOT;
#pragma unroll
    for (int g = p * (L / PH); g < (p + 1) * (L / PH); ++g) {
      if (g < KC * (AF / 8)) {
        const int c = g / (AF / 8), q = g % (AF / 8);
        const int f = q * 8 + w;
        gll16(A + (((size_t)(rtA0 + f) * TKA + kt * KC + c) << 10) + l * 16,
              dst + (c * AF + f) * 1024 + l * 16);
      } else {
        const int h = g - KC * (AF / 8);
        const int c = h / (BF / 8), q = h % (BF / 8);
        const int f = q * 8 + w;
        gll16(B + (((size_t)(rtB0 + f) * TKB + kt * KC + c) << 10) + l * 16,
              dst + (KC * AF + c * BF + f) * 1024 + l * 16);
      }
    }
  };
  auto stage_all = [&](int slot, int kt) {
#pragma unroll
    for (int p = 0; p < PH; ++p) stage_part(slot, kt, p);
  };

  // Prologue: 3 slots in flight; publish slot 0 (wait only its L loads).
  stage_all(0, 0); stage_all(1, 1); stage_all(2, 2);
  asm volatile("s_waitcnt vmcnt(%0) lgkmcnt(0)\ns_barrier" :: "n"(2 * L) : "memory");

  short8 bf[KC][BWF];
#pragma unroll 4
  for (int kt = 0; kt < KIT; ++kt) {
    const char* bA = lds + (kt & 3) * SLOT;
    const char* bB = bA + KC * AF * 1024;
#pragma unroll
    for (int p = 0; p < PH; ++p) {
      short8 af[KC][AC];
#pragma unroll
      for (int c = 0; c < KC; ++c)
#pragma unroll
        for (int i = 0; i < AC; ++i)
          af[c][i] = *(const short8*)(bA + (c * AF + wm * AWF + p * AC + i) * 1024 + l * 16);
      if (p == 0) {
#pragma unroll
        for (int c = 0; c < KC; ++c)
#pragma unroll
          for (int j = 0; j < BWF; ++j)
            bf[c][j] = *(const short8*)(bB + (c * BF + wn * BWF + j) * 1024 + l * 16);
      }
      if (kt + 3 < KIT) stage_part((kt + 3) & 3, kt + 3, p);   // 3-ahead prefetch

      asm volatile("s_barrier" ::: "memory");
      asm volatile("s_waitcnt lgkmcnt(0)" ::: "memory");
      __builtin_amdgcn_s_setprio(1);
#pragma unroll
      for (int c = 0; c < KC; ++c)
#pragma unroll
        for (int i = 0; i < AC; ++i)
#pragma unroll
          for (int j = 0; j < BWF; ++j)
            acc[p * AC + i][j] = __builtin_amdgcn_mfma_f32_16x16x32_bf16(
                af[c][i], bf[c][j], acc[p * AC + i][j], 0, 0, 0);
      __builtin_amdgcn_s_setprio(0);

      if (p == PH - 1) {        // slot-closing barrier: counted vmcnt ladder
        if (kt + 3 < KIT)
          asm volatile("s_waitcnt vmcnt(%0)\ns_barrier" :: "n"(2 * L) : "memory");
        else if (kt + 2 < KIT)
          asm volatile("s_waitcnt vmcnt(%0)\ns_barrier" :: "n"(L) : "memory");
        else if (kt + 1 < KIT)
          asm volatile("s_waitcnt vmcnt(0)\ns_barrier" ::: "memory");
        // last slot: fall through to epilogue (all gll16 retired by ladder)
      } else {
        asm volatile("s_barrier" ::: "memory");
      }
    }
  }
}

// ---- K0: setup: X->XbF frags, W->WF frags (transposed) --------------------
__global__ __launch_bounds__(256) void setup_kernel(
    const float* __restrict__ X, const float* __restrict__ Wq,
    const float* __restrict__ Wk, const float* __restrict__ Wv,
    short8* __restrict__ XbF, short8* __restrict__ WF)
{
  const int flat = blockIdx.x * 256 + threadIdx.x;   // 0..524287
  {
    const int tile = flat >> 6, l = flat & 63;
    const int row = (tile >> 4) * 16 + (l & 15);
    const int k0  = (tile & 15) * 32 + (l >> 4) * 8;
    const float4 v0 = *(const float4*)(X + (size_t)row * DIM + k0);
    const float4 v1 = *(const float4*)(X + (size_t)row * DIM + k0 + 4);
    short8 o;
    o[0] = (short)f2b(v0.x); o[1] = (short)f2b(v0.y);
    o[2] = (short)f2b(v0.z); o[3] = (short)f2b(v0.w);
    o[4] = (short)f2b(v1.x); o[5] = (short)f2b(v1.y);
    o[6] = (short)f2b(v1.z); o[7] = (short)f2b(v1.w);
    XbF[flat] = o;
  }
  if (flat < 3 * 32768) {                            // W -> WF (rows=n, K=k)
    const int z = flat >> 15, within = flat & 32767;
    const float* W = (z == 0) ? Wq : (z == 1) ? Wk : Wv;
    const int tile = within >> 6, l = within & 63;
    const int n  = (tile >> 4) * 16 + (l & 15);
    const int k0 = (tile & 15) * 32 + (l >> 4) * 8;
    short8 o;
#pragma unroll
    for (int e = 0; e < 8; ++e)
      o[e] = (short)f2b(W[(size_t)(k0 + e) * DIM + n]);
    WF[flat] = o;
  }
}

// ---- K1: QKV. 256x256 tiles. XCD-swizzled 1-D grid: xcd = x&7 so all 6
//      consumers (y in 2, z in 3) of an X-panel are co-XCD. -----------------
__global__ __launch_bounds__(512, 2) void qkv_kernel(
    const short8* __restrict__ XbF, const short8* __restrict__ WF,
    const float* __restrict__ bq, const float* __restrict__ bk,
    const float* __restrict__ bv,
    unsigned short* __restrict__ QF, unsigned short* __restrict__ KF,
    unsigned short* __restrict__ VF)
{
  __shared__ char lds[131072];   // 4 x 32 KB slots
  const int n = blockIdx.x;                      // 0..191
  const int xcd = n & 7, i = n >> 3;             // i: 0..23
  const int x = xcd + 8 * (i & 3);               // s-tile 0..31
  const int zy = i >> 2;                         // 0..5
  const int z = zy >> 1, y = zy & 1;             // z: 0..2, y: 0..1
  const int lane = threadIdx.x & 63, w = threadIdx.x >> 6;
  const int wm = w & 1, wn = w >> 1;             // WM=2, WN=4
  const char* Xc = (const char*)XbF;
  const char* Wc = (const char*)WF;
  floatx4 acc[8][4] = {};

  if (z < 2) {
    fgemm_8p<16, 16, 2, 4, 1, 2, 16>(Wc + (size_t)z * 524288, y * 16, 16,
                                     Xc, x * 16, 16, lds, acc);
    const float* bias = z ? bk : bq;
    unsigned short* OF = z ? KF : QF;
    const int dbase = y * 256 + wm * 128;
    const int sbase = x * 256 + wn * 64;
#pragma unroll
    for (int i2 = 0; i2 < 8; ++i2) {
      const int d0 = dbase + i2 * 16 + (lane >> 4) * 4;
      const float4 b4 = *(const float4*)(bias + d0);
#pragma unroll
      for (int j = 0; j < 4; ++j) {
        const int s = sbase + j * 16 + (lane & 15);
        ushort4 pk;
        pk.x = f2b(acc[i2][j][0] + b4.x);
        pk.y = f2b(acc[i2][j][1] + b4.y);
        pk.z = f2b(acc[i2][j][2] + b4.z);
        pk.w = f2b(acc[i2][j][3] + b4.w);
        *(ushort4*)(OF + (size_t)((s >> 4) * 16 + (d0 >> 5)) * 512 +
                    ((((d0 & 31) >> 3) << 4) | (s & 15)) * 8 + (d0 & 7)) = pk;
      }
    }
  } else {
    fgemm_8p<16, 16, 2, 4, 1, 2, 16>(Xc, x * 16, 16,
                                     Wc + 2 * 524288, y * 16, 16, lds, acc);
    const int sbase = x * 256 + wm * 128;
    const int dbase = y * 256 + wn * 64;
#pragma unroll
    for (int i2 = 0; i2 < 8; ++i2) {
      const int s0 = sbase + i2 * 16 + (lane >> 4) * 4;
      const int bt = s0 >> 11, t0 = s0 & 2047;
#pragma unroll
      for (int j = 0; j < 4; ++j) {
        const int d = dbase + j * 16 + (lane & 15);
        const float bn = bv[d];
        ushort4 pk;
        pk.x = f2b(acc[i2][j][0] + bn);
        pk.y = f2b(acc[i2][j][1] + bn);
        pk.z = f2b(acc[i2][j][2] + bn);
        pk.w = f2b(acc[i2][j][3] + bn);
        *(ushort4*)(VF + (size_t)bt * DIM * SEQ +
                    (size_t)((d >> 4) * 64 + (t0 >> 5)) * 512 +
                    ((((t0 & 31) >> 3) << 4) | (d & 15)) * 8 + (t0 & 7)) = pk;
      }
    }
  }
}

// ---- K2: S^T = K Q^T, 256t x 256s tiles; exp epilogue -> ScF + prow -------
// XCD-swizzle: xcd = 2b + (x>>2): one batch per XCD-pair; Q-panel's 8
// consumers (y) co-XCD; per-XCD L2 set ~3 MB (fits 4 MB).
__global__ __launch_bounds__(512, 2) void scores_kernel(
    const unsigned short* __restrict__ QF, const unsigned short* __restrict__ KF,
    unsigned short* __restrict__ ScF, float* __restrict__ prow)
{
  __shared__ char lds[131072];   // 4 x 32 KB slots
  const int n = blockIdx.x;                      // 0..255
  const int xcd = n & 7, i = n >> 3;             // i: 0..31
  const int b = xcd >> 1;
  const int x = (xcd & 1) * 4 + (i & 3);         // s-tile 0..7
  const int y = i >> 2;                          // t-tile 0..7
  const int lane = threadIdx.x & 63, w = threadIdx.x >> 6;
  const int wm = w & 1, wn = w >> 1;             // WM=2, WN=4
  floatx4 acc[8][4] = {};
  fgemm_8p<16, 16, 2, 4, 1, 2, 16>((const char*)KF + (size_t)b * 2097152, y * 16, 16,
                                   (const char*)QF + (size_t)b * 2097152, x * 16, 16,
                                   lds, acc);

  unsigned short* S = ScF + (size_t)b * SEQ * SEQ;
  const float scale = 0.044194173824159216f;  // 1/sqrt(512)
  const int tbase = y * 256 + wm * 128;
  const int sbase = x * 256 + wn * 64;
  float colsum[4] = {0.f, 0.f, 0.f, 0.f};
#pragma unroll
  for (int i2 = 0; i2 < 8; ++i2) {
    const int t0 = tbase + i2 * 16 + (lane >> 4) * 4;
#pragma unroll
    for (int j = 0; j < 4; ++j) {
      const int s = sbase + j * 16 + (lane & 15);
      float e0 = __expf(acc[i2][j][0] * scale);
      float e1 = __expf(acc[i2][j][1] * scale);
      float e2 = __expf(acc[i2][j][2] * scale);
      float e3 = __expf(acc[i2][j][3] * scale);
      colsum[j] += (e0 + e1) + (e2 + e3);
      ushort4 pk;
      pk.x = f2b(e0); pk.y = f2b(e1); pk.z = f2b(e2); pk.w = f2b(e3);
      *(ushort4*)(S + (size_t)((s >> 4) * 64 + (t0 >> 5)) * 512 +
                  ((((t0 & 31) >> 3) << 4) | (s & 15)) * 8 + (t0 & 7)) = pk;
    }
  }
#pragma unroll
  for (int j = 0; j < 4; ++j) {
    colsum[j] += __shfl_xor(colsum[j], 16, 64);
    colsum[j] += __shfl_xor(colsum[j], 32, 64);
  }
  if (lane < 16) {   // partial rowsum slice q = y*2+wm (t-range q*128..+127)
    float* dst = prow + ((size_t)(y * 2 + wm) * BATCH + b) * SEQ + sbase + lane;
#pragma unroll
    for (int j = 0; j < 4; ++j) dst[j * 16] = colsum[j];
  }
}

// ---- K3: out[s][d] = (ScF . VF) / rowsum[s]; 128x128 tile, BK=64 ----------
// XCD-swizzle: xcd = 2b + (x>>3): Sc-stripe's 4 consumers (y) co-XCD.
__global__ __launch_bounds__(512, 2) void pv_kernel(
    const unsigned short* __restrict__ ScF, const unsigned short* __restrict__ VF,
    const float* __restrict__ prow, float* __restrict__ out)
{
  __shared__ char lds[131072];   // 4 x 32 KB slots
  __shared__ float rinv[128];
  const int n = blockIdx.x;                      // 0..255
  const int xcd = n & 7, i = n >> 3;             // i: 0..31
  const int b = xcd >> 1;
  const int x = (xcd & 1) * 8 + (i & 7);         // s-stripe 0..15
  const int y = i >> 3;                          // d-tile 0..3
  const int t = threadIdx.x;
  if (t < 128) {   // rowsum = sum of 16 partial slices; drained before fgemm
    const int s = x * 128 + t;
    float r = 0.f;
#pragma unroll
    for (int q = 0; q < 16; ++q) r += prow[((size_t)q * BATCH + b) * SEQ + s];
    rinv[t] = 1.f / r;
  }
  const int lane = threadIdx.x & 63, w = threadIdx.x >> 6;
  const int wm = w & 1, wn = w >> 1;             // WM=2, WN=4
  floatx4 acc[4][2] = {};
  fgemm_8p<8, 8, 2, 4, 2, 1, 32>((const char*)ScF + (size_t)b * 8388608, x * 8, 64,
                                 (const char*)VF + (size_t)b * 2097152, y * 8, 64,
                                 lds, acc);

  const int mbase = x * 128 + wm * 64;
  const int dbase = y * 128 + wn * 32;
#pragma unroll
  for (int i2 = 0; i2 < 4; ++i2) {
    const int r0 = wm * 64 + i2 * 16 + (lane >> 4) * 4;
    const int m0 = mbase + i2 * 16 + (lane >> 4) * 4;
    const float inv0 = rinv[r0], inv1 = rinv[r0 + 1], inv2 = rinv[r0 + 2], inv3 = rinv[r0 + 3];
#pragma unroll
    for (int j = 0; j < 2; ++j) {
      const int d = dbase + j * 16 + (lane & 15);
      float* o = out + ((size_t)b * SEQ + m0) * DIM + d;
      o[0 * DIM] = acc[i2][j][0] * inv0;
      o[1 * DIM] = acc[i2][j][1] * inv1;
      o[2 * DIM] = acc[i2][j][2] * inv2;
      o[3 * DIM] = acc[i2][j][3] * inv3;
    }
  }
}

extern "C" void kernel_launch(void* const* d_in, const int* in_sizes, int n_in,
                              void* d_out, int out_size, void* d_ws, size_t ws_size,
                              hipStream_t stream) {
  const float* X  = (const float*)d_in[0];
  const float* Wq = (const float*)d_in[1];
  const float* bq = (const float*)d_in[2];
  const float* Wk = (const float*)d_in[3];
  const float* bk = (const float*)d_in[4];
  const float* Wv = (const float*)d_in[5];
  const float* bv = (const float*)d_in[6];
  float* out = (float*)d_out;
  char* ws = (char*)d_ws;

  // workspace layout (bytes). prow aliases XbF (XbF is dead after qkv; prow
  // is fully written by scores before pv reads it).
  short8* XbF = (short8*)(ws + 0);                    //  8 MB   (rows=b*S+s, K=512)
  float*  prow = (float*)(ws + 0);                    // 512 KB  [16][B][SEQ] partial rowsums
  short8* WF  = (short8*)(ws + 8388608);              //  1.5 MB (rows=n, K=512, x3)
  unsigned short* QF  = (unsigned short*)(ws + 9961472);   //  8 MB (rows=s, K=d)
  unsigned short* KF  = (unsigned short*)(ws + 18350080);  //  8 MB (rows=s, K=d)
  unsigned short* VF  = (unsigned short*)(ws + 26738688);  //  8 MB (rows=d, K=t, per b)
  unsigned short* ScF = (unsigned short*)(ws + 35127296);  // 32 MB (rows=s, K=t, per b)

  setup_kernel<<<dim3(2048), 256, 0, stream>>>(X, Wq, Wk, Wv, XbF, WF);
  qkv_kernel<<<dim3(192), 512, 0, stream>>>(XbF, WF, bq, bk, bv, QF, KF, VF);
  scores_kernel<<<dim3(256), 512, 0, stream>>>(QF, KF, ScF, prow);
  pv_kernel<<<dim3(256), 512, 0, stream>>>(ScF, VF, prow, out);
}

// Round 5
// 137.732 us; speedup vs baseline: 1.8937x; 1.0367x over previous
//
#include <hip/hip_runtime.h>
#include <hip/hip_bf16.h>
#include <stdint.h>

#define SEQ   2048
#define DIM   512
#define BATCH 4

typedef __attribute__((ext_vector_type(8))) short  short8;
typedef __attribute__((ext_vector_type(4))) float  floatx4;

static __device__ __forceinline__ unsigned short f2b(float f) {
  return __builtin_bit_cast(unsigned short, __float2bfloat16(f));
}

// async 16B/lane global->LDS (global_load_lds_dwordx4)
static __device__ __forceinline__ void gll16(const void* g, void* l) {
  __builtin_amdgcn_global_load_lds(
      (__attribute__((address_space(1))) void*)(uintptr_t)g,
      (__attribute__((address_space(3))) void*)l, 16, 0, 0);
}

// ---------------------------------------------------------------------------
// Fragment-linear layout (verified): logical [R rows][K] bf16 matrix as 1KB
// fragments of 16 rows x 32 k; frag index = rt*TK + kt; within a frag, lane l
// owns bytes l*16..+15 = MFMA operand row rt*16+(l&15), k octet (l>>4).
// ---------------------------------------------------------------------------

// Pipelined fragment GEMM, 4-wave (NW=4) variant sized for 2 blocks/CU:
// 3-slot LDS ring (24 KB slots -> 72 KB), depth-2 prefetch, counted vmcnt
// ladder (L -> 0), per-phase {ds_read || stage -> barrier -> lgkmcnt(0) ->
// setprio(1) MFMA setprio(0) -> barrier}.  Cross-block TLP (2 blocks/CU)
// hides fill/drain/barrier-skew.  Callers guarantee no other VMEM op is
// outstanding when the counted waits execute.
template <int AF, int BF, int WM, int WN, int KC, int PH, int KIT, int NW>
__device__ __forceinline__ void fgemm_p(
    const char* __restrict__ A, int rtA0, int TKA,
    const char* __restrict__ B, int rtB0, int TKB,
    char* lds, floatx4 (&acc)[AF / WM][BF / WN])
{
  constexpr int AWF  = AF / WM, BWF = BF / WN;
  constexpr int SLOT = (AF + BF) * KC * 1024;
  constexpr int L    = KC * (AF / NW + BF / NW);  // gll16 per wave per slot
  constexpr int AC   = AWF / PH;                  // A-frag rows per phase
  static_assert(KIT >= 3, "pipeline needs >=3 K-slots");
  static_assert(AF % NW == 0 && BF % NW == 0, "frag rows must divide waves");
  static_assert(AWF % PH == 0 && L % PH == 0, "phase split must divide");
  const int tid = threadIdx.x;
  const int w = tid >> 6, l = tid & 63;
  const int wm = w % WM, wn = w / WM;

  auto stage_part = [&](char* dst, int kt, int p) {
#pragma unroll
    for (int g = p * (L / PH); g < (p + 1) * (L / PH); ++g) {
      if (g < KC * (AF / NW)) {
        const int c = g / (AF / NW), q = g % (AF / NW);
        const int f = q * NW + w;
        gll16(A + (((size_t)(rtA0 + f) * TKA + kt * KC + c) << 10) + l * 16,
              dst + (c * AF + f) * 1024 + l * 16);
      } else {
        const int h = g - KC * (AF / NW);
        const int c = h / (BF / NW), q = h % (BF / NW);
        const int f = q * NW + w;
        gll16(B + (((size_t)(rtB0 + f) * TKB + kt * KC + c) << 10) + l * 16,
              dst + (KC * AF + c * BF + f) * 1024 + l * 16);
      }
    }
  };

  // Prologue: 2 slots in flight; publish slot 0 (wait only its L loads).
#pragma unroll
  for (int p = 0; p < PH; ++p) stage_part(lds, 0, p);
#pragma unroll
  for (int p = 0; p < PH; ++p) stage_part(lds + SLOT, 1, p);
  asm volatile("s_waitcnt vmcnt(%0) lgkmcnt(0)\ns_barrier" :: "n"(L) : "memory");

  short8 bf[KC][BWF];
  int cs = 0;                               // current ring slot (mod 3)
#pragma unroll 2
  for (int kt = 0; kt < KIT; ++kt) {
    const char* bA = lds + cs * SLOT;
    const char* bB = bA + KC * AF * 1024;
    int ns = cs - 1; if (ns < 0) ns = 2;    // slot of kt+2 == (cs+2)%3
    char* pdst = lds + ns * SLOT;
#pragma unroll
    for (int p = 0; p < PH; ++p) {
      short8 af[KC][AC];
#pragma unroll
      for (int c = 0; c < KC; ++c)
#pragma unroll
        for (int i = 0; i < AC; ++i)
          af[c][i] = *(const short8*)(bA + (c * AF + wm * AWF + p * AC + i) * 1024 + l * 16);
      if (p == 0) {
#pragma unroll
        for (int c = 0; c < KC; ++c)
#pragma unroll
          for (int j = 0; j < BWF; ++j)
            bf[c][j] = *(const short8*)(bB + (c * BF + wn * BWF + j) * 1024 + l * 16);
      }
      if (kt + 2 < KIT) stage_part(pdst, kt + 2, p);   // depth-2 prefetch

      asm volatile("s_barrier" ::: "memory");
      asm volatile("s_waitcnt lgkmcnt(0)" ::: "memory");
      __builtin_amdgcn_s_setprio(1);
#pragma unroll
      for (int c = 0; c < KC; ++c)
#pragma unroll
        for (int i = 0; i < AC; ++i)
#pragma unroll
          for (int j = 0; j < BWF; ++j)
            acc[p * AC + i][j] = __builtin_amdgcn_mfma_f32_16x16x32_bf16(
                af[c][i], bf[c][j], acc[p * AC + i][j], 0, 0, 0);
      __builtin_amdgcn_s_setprio(0);

      if (p == PH - 1) {        // slot-closing barrier: counted vmcnt ladder
        if (kt + 2 < KIT)
          asm volatile("s_waitcnt vmcnt(%0)\ns_barrier" :: "n"(L) : "memory");
        else if (kt + 1 < KIT)
          asm volatile("s_waitcnt vmcnt(0)\ns_barrier" ::: "memory");
        // last slot: fall through to epilogue (all gll16 retired by ladder)
      } else {
        asm volatile("s_barrier" ::: "memory");
      }
    }
    ++cs; if (cs == 3) cs = 0;
  }
}

// ---- K0: setup: X->XbF frags, W->WF frags (transposed) --------------------
__global__ __launch_bounds__(256) void setup_kernel(
    const float* __restrict__ X, const float* __restrict__ Wq,
    const float* __restrict__ Wk, const float* __restrict__ Wv,
    short8* __restrict__ XbF, short8* __restrict__ WF)
{
  const int flat = blockIdx.x * 256 + threadIdx.x;   // 0..524287
  {
    const int tile = flat >> 6, l = flat & 63;
    const int row = (tile >> 4) * 16 + (l & 15);
    const int k0  = (tile & 15) * 32 + (l >> 4) * 8;
    const float4 v0 = *(const float4*)(X + (size_t)row * DIM + k0);
    const float4 v1 = *(const float4*)(X + (size_t)row * DIM + k0 + 4);
    short8 o;
    o[0] = (short)f2b(v0.x); o[1] = (short)f2b(v0.y);
    o[2] = (short)f2b(v0.z); o[3] = (short)f2b(v0.w);
    o[4] = (short)f2b(v1.x); o[5] = (short)f2b(v1.y);
    o[6] = (short)f2b(v1.z); o[7] = (short)f2b(v1.w);
    XbF[flat] = o;
  }
  if (flat < 3 * 32768) {                            // W -> WF (rows=n, K=k)
    const int z = flat >> 15, within = flat & 32767;
    const float* W = (z == 0) ? Wq : (z == 1) ? Wk : Wv;
    const int tile = within >> 6, l = within & 63;
    const int n  = (tile >> 4) * 16 + (l & 15);
    const int k0 = (tile & 15) * 32 + (l >> 4) * 8;
    short8 o;
#pragma unroll
    for (int e = 0; e < 8; ++e)
      o[e] = (short)f2b(W[(size_t)(k0 + e) * DIM + n]);
    WF[flat] = o;
  }
}

// ---- K1: QKV. 256x128 tiles, 4 waves, 2 blocks/CU. Chunked XCD map. -------
// n<256: z=0,1: C[d][s] (A=WF 256d, B=XbF 128s). n>=256: C[s][d] (A=XbF 256s,
// B=WFv 128d).
__global__ __launch_bounds__(256, 2) void qkv_kernel(
    const short8* __restrict__ XbF, const short8* __restrict__ WF,
    const float* __restrict__ bq, const float* __restrict__ bk,
    const float* __restrict__ bv,
    unsigned short* __restrict__ QF, unsigned short* __restrict__ KF,
    unsigned short* __restrict__ VF)
{
  __shared__ char lds[73728];   // 3 x 24 KB ring
  const int blk = blockIdx.x;                    // 0..383
  const int n = (blk & 7) * 48 + (blk >> 3);     // chunked: 48 per XCD
  const int lane = threadIdx.x & 63, w = threadIdx.x >> 6;
  const int wm = w & 1, wn = w >> 1;             // WM=2, WN=2
  const char* Xc = (const char*)XbF;
  const char* Wc = (const char*)WF;
  floatx4 acc[8][4] = {};

  if (n < 256) {
    const int z = n >> 7, y = (n >> 6) & 1, x = n & 63;   // x: s-tile(128)
    fgemm_p<16, 8, 2, 2, 1, 2, 16, 4>(Wc + (size_t)z * 524288, y * 16, 16,
                                      Xc, x * 8, 16, lds, acc);
    const float* bias = z ? bk : bq;
    unsigned short* OF = z ? KF : QF;
    const int dbase = y * 256 + wm * 128;
    const int sbase = x * 128 + wn * 64;
#pragma unroll
    for (int i2 = 0; i2 < 8; ++i2) {
      const int d0 = dbase + i2 * 16 + (lane >> 4) * 4;
      const float4 b4 = *(const float4*)(bias + d0);
#pragma unroll
      for (int j = 0; j < 4; ++j) {
        const int s = sbase + j * 16 + (lane & 15);
        ushort4 pk;
        pk.x = f2b(acc[i2][j][0] + b4.x);
        pk.y = f2b(acc[i2][j][1] + b4.y);
        pk.z = f2b(acc[i2][j][2] + b4.z);
        pk.w = f2b(acc[i2][j][3] + b4.w);
        *(ushort4*)(OF + (size_t)((s >> 4) * 16 + (d0 >> 5)) * 512 +
                    ((((d0 & 31) >> 3) << 4) | (s & 15)) * 8 + (d0 & 7)) = pk;
      }
    }
  } else {
    const int m = n - 256;                         // 0..127
    const int x = m >> 2, y = m & 3;               // x: s-tile(256), y: d-tile(128)
    fgemm_p<16, 8, 2, 2, 1, 2, 16, 4>(Xc, x * 16, 16,
                                      Wc + 2 * 524288, y * 8, 16, lds, acc);
    const int sbase = x * 256 + wm * 128;
    const int dbase = y * 128 + wn * 64;
#pragma unroll
    for (int i2 = 0; i2 < 8; ++i2) {
      const int s0 = sbase + i2 * 16 + (lane >> 4) * 4;
      const int bt = s0 >> 11, t0 = s0 & 2047;
#pragma unroll
      for (int j = 0; j < 4; ++j) {
        const int d = dbase + j * 16 + (lane & 15);
        const float bn = bv[d];
        ushort4 pk;
        pk.x = f2b(acc[i2][j][0] + bn);
        pk.y = f2b(acc[i2][j][1] + bn);
        pk.z = f2b(acc[i2][j][2] + bn);
        pk.w = f2b(acc[i2][j][3] + bn);
        *(ushort4*)(VF + (size_t)bt * DIM * SEQ +
                    (size_t)((d >> 4) * 64 + (t0 >> 5)) * 512 +
                    ((((t0 & 31) >> 3) << 4) | (d & 15)) * 8 + (t0 & 7)) = pk;
      }
    }
  }
}

// ---- K2: S^T = K Q^T, 256t x 128s tiles; exp epilogue -> ScF + prow -------
// 512 blocks (2/CU). Chunked XCD map: 64/XCD => half a batch per XCD
// (Q panels + K panels ~3 MB, L2-resident).
__global__ __launch_bounds__(256, 2) void scores_kernel(
    const unsigned short* __restrict__ QF, const unsigned short* __restrict__ KF,
    unsigned short* __restrict__ ScF, float* __restrict__ prow)
{
  __shared__ char lds[73728];   // 3 x 24 KB ring
  const int blk = blockIdx.x;                    // 0..511
  const int n = (blk & 7) * 64 + (blk >> 3);
  const int b = n >> 7, t = n & 127;
  const int y = t >> 4, x = t & 15;              // y: t-tile(256), x: s-tile(128)
  const int lane = threadIdx.x & 63, w = threadIdx.x >> 6;
  const int wm = w & 1, wn = w >> 1;             // WM=2, WN=2
  floatx4 acc[8][4] = {};
  fgemm_p<16, 8, 2, 2, 1, 2, 16, 4>((const char*)KF + (size_t)b * 2097152, y * 16, 16,
                                    (const char*)QF + (size_t)b * 2097152, x * 8, 16,
                                    lds, acc);

  unsigned short* S = ScF + (size_t)b * SEQ * SEQ;
  const float scale = 0.044194173824159216f;  // 1/sqrt(512)
  const int tbase = y * 256 + wm * 128;
  const int sbase = x * 128 + wn * 64;
  float colsum[4] = {0.f, 0.f, 0.f, 0.f};
#pragma unroll
  for (int i2 = 0; i2 < 8; ++i2) {
    const int t0 = tbase + i2 * 16 + (lane >> 4) * 4;
#pragma unroll
    for (int j = 0; j < 4; ++j) {
      const int s = sbase + j * 16 + (lane & 15);
      float e0 = __expf(acc[i2][j][0] * scale);
      float e1 = __expf(acc[i2][j][1] * scale);
      float e2 = __expf(acc[i2][j][2] * scale);
      float e3 = __expf(acc[i2][j][3] * scale);
      colsum[j] += (e0 + e1) + (e2 + e3);
      ushort4 pk;
      pk.x = f2b(e0); pk.y = f2b(e1); pk.z = f2b(e2); pk.w = f2b(e3);
      *(ushort4*)(S + (size_t)((s >> 4) * 64 + (t0 >> 5)) * 512 +
                  ((((t0 & 31) >> 3) << 4) | (s & 15)) * 8 + (t0 & 7)) = pk;
    }
  }
#pragma unroll
  for (int j = 0; j < 4; ++j) {
    colsum[j] += __shfl_xor(colsum[j], 16, 64);
    colsum[j] += __shfl_xor(colsum[j], 32, 64);
  }
  if (lane < 16) {   // partial rowsum slice q = y*2+wm (t-range q*128..+127)
    float* dst = prow + ((size_t)(y * 2 + wm) * BATCH + b) * SEQ + sbase + lane;
#pragma unroll
    for (int j = 0; j < 4; ++j) dst[j * 16] = colsum[j];
  }
}

// ---- K3: out[s][d] = (ScF . VF) / rowsum[s]; 128s x 64d tile, BK=64 -------
// 512 blocks (2/CU). Chunked XCD map: 64/XCD => half batch (V L2-resident).
__global__ __launch_bounds__(256, 2) void pv_kernel(
    const unsigned short* __restrict__ ScF, const unsigned short* __restrict__ VF,
    const float* __restrict__ prow, float* __restrict__ out)
{
  __shared__ char lds[73728];   // 3 x 24 KB ring
  __shared__ float rinv[128];
  const int blk = blockIdx.x;                    // 0..511
  const int n = (blk & 7) * 64 + (blk >> 3);
  const int b = n >> 7, r = n & 127;
  const int x = r >> 3, y = r & 7;               // x: s-stripe(128), y: d-tile(64)
  const int t = threadIdx.x;
  if (t < 128) {   // rowsum = sum of 16 partial slices; drained before fgemm
    const int s = x * 128 + t;
    float rr = 0.f;
#pragma unroll
    for (int q = 0; q < 16; ++q) rr += prow[((size_t)q * BATCH + b) * SEQ + s];
    rinv[t] = 1.f / rr;
  }
  const int lane = threadIdx.x & 63, w = threadIdx.x >> 6;
  const int wm = w & 1, wn = w >> 1;             // WM=2, WN=2
  floatx4 acc[4][2] = {};
  fgemm_p<8, 4, 2, 2, 2, 1, 32, 4>((const char*)ScF + (size_t)b * 8388608, x * 8, 64,
                                   (const char*)VF + (size_t)b * 2097152, y * 4, 64,
                                   lds, acc);

  const int mbase = x * 128 + wm * 64;
  const int dbase = y * 64 + wn * 32;
#pragma unroll
  for (int i2 = 0; i2 < 4; ++i2) {
    const int r0 = wm * 64 + i2 * 16 + (lane >> 4) * 4;
    const int m0 = mbase + i2 * 16 + (lane >> 4) * 4;
    const float inv0 = rinv[r0], inv1 = rinv[r0 + 1], inv2 = rinv[r0 + 2], inv3 = rinv[r0 + 3];
#pragma unroll
    for (int j = 0; j < 2; ++j) {
      const int d = dbase + j * 16 + (lane & 15);
      float* o = out + ((size_t)b * SEQ + m0) * DIM + d;
      o[0 * DIM] = acc[i2][j][0] * inv0;
      o[1 * DIM] = acc[i2][j][1] * inv1;
      o[2 * DIM] = acc[i2][j][2] * inv2;
      o[3 * DIM] = acc[i2][j][3] * inv3;
    }
  }
}

extern "C" void kernel_launch(void* const* d_in, const int* in_sizes, int n_in,
                              void* d_out, int out_size, void* d_ws, size_t ws_size,
                              hipStream_t stream) {
  const float* X  = (const float*)d_in[0];
  const float* Wq = (const float*)d_in[1];
  const float* bq = (const float*)d_in[2];
  const float* Wk = (const float*)d_in[3];
  const float* bk = (const float*)d_in[4];
  const float* Wv = (const float*)d_in[5];
  const float* bv = (const float*)d_in[6];
  float* out = (float*)d_out;
  char* ws = (char*)d_ws;

  // workspace layout (bytes). prow aliases XbF (XbF dead after qkv; prow is
  // fully written by scores before pv reads it).
  short8* XbF = (short8*)(ws + 0);                    //  8 MB   (rows=b*S+s, K=512)
  float*  prow = (float*)(ws + 0);                    // 512 KB  [16][B][SEQ] partial rowsums
  short8* WF  = (short8*)(ws + 8388608);              //  1.5 MB (rows=n, K=512, x3)
  unsigned short* QF  = (unsigned short*)(ws + 9961472);   //  8 MB (rows=s, K=d)
  unsigned short* KF  = (unsigned short*)(ws + 18350080);  //  8 MB (rows=s, K=d)
  unsigned short* VF  = (unsigned short*)(ws + 26738688);  //  8 MB (rows=d, K=t, per b)
  unsigned short* ScF = (unsigned short*)(ws + 35127296);  // 32 MB (rows=s, K=t, per b)

  setup_kernel<<<dim3(2048), 256, 0, stream>>>(X, Wq, Wk, Wv, XbF, WF);
  qkv_kernel<<<dim3(384), 256, 0, stream>>>(XbF, WF, bq, bk, bv, QF, KF, VF);
  scores_kernel<<<dim3(512), 256, 0, stream>>>(QF, KF, ScF, prow);
  pv_kernel<<<dim3(512), 256, 0, stream>>>(ScF, VF, prow, out);
}